// Round 28
// baseline (55.311 us; speedup 1.0000x reference)
//
#include <hip/hip_runtime.h>
#include <math.h>

#define BT    8192
#define TSEQ  2048
#define DIN   1024
#define DK    64

typedef __attribute__((ext_vector_type(8))) short bf16x8;
typedef __attribute__((ext_vector_type(4))) short bf16x4;
typedef __attribute__((ext_vector_type(4))) float f32x4;

static __device__ inline unsigned short f2bf(float f) {
    union { float f; unsigned u; } v; v.f = f;
    unsigned r = v.u + 0x7fff + ((v.u >> 16) & 1);   // RNE
    return (unsigned short)(r >> 16);
}

static __device__ inline bf16x4 cvt4(float4 a) {
    bf16x4 r;
    r[0] = (short)f2bf(a.x); r[1] = (short)f2bf(a.y);
    r[2] = (short)f2bf(a.z); r[3] = (short)f2bf(a.w);
    return r;
}

// -------- WTB chunk-major: WTB[(kc*192 + mat*64+n)*64 + (k&63)] = W[k][n] ----
// Direct B-fragment loads from this layout are 64-B segments at 128-B stride
// inside a 12-KB chunk (K-load class, measured cheap) -> no LDS roundtrip.
__global__ __launch_bounds__(256) void wt_kernel(
    const float* __restrict__ Wq, const float* __restrict__ Wk,
    const float* __restrict__ Wv, unsigned short* __restrict__ WTB)
{
    __shared__ float ws[64][65];
    const int tid = threadIdx.x;
    const int mat = blockIdx.x >> 4;               // 0..2
    const int kc  = blockIdx.x & 15;               // 64-k chunk
    const int k0  = kc << 6;
    const float* W = (mat == 0) ? Wq : ((mat == 1) ? Wk : Wv);

    const int j = tid & 63;
    for (int i = tid >> 6; i < 64; i += 4)
        ws[i][j] = W[(size_t)(k0 + i) * DK + j];
    __syncthreads();

    const int n  = tid & 63;
    const int c0 = (tid >> 6) << 4;
    unsigned short* dst = WTB + ((size_t)kc * 192 + mat * 64 + n) * 64 + c0;
    #pragma unroll
    for (int c = 0; c < 16; ++c) dst[c] = f2bf(ws[c0 + c][n]);
}

// ---------------- MFMA projection: direct fragment loads, no wtb LDS --------
// Per chunk: 2 ds_read (A from xs) + 6 global B-frag loads + 6 MFMA. Zero
// intra-loop LDS dependence -> full cross-chunk ILP. LDS 33 KB (xs only).
__global__ __launch_bounds__(256, 2) void proj_kernel(
    const float* __restrict__ x, const unsigned short* __restrict__ WTB,
    unsigned short* __restrict__ Qb, unsigned short* __restrict__ Kb,
    unsigned short* __restrict__ VT)
{
    __shared__ unsigned short xs[16][1032];        // 33.0 KB
    const int tid = threadIdx.x;
    const int m0 = blockIdx.x * 16;

    {
        const int r = tid >> 4;
        const int c = (tid & 15) << 2;
        const float* src = x + (size_t)(m0 + r) * DIN + c;
        float4 tmp[16];
        #pragma unroll
        for (int s = 0; s < 16; ++s) tmp[s] = *(const float4*)(src + s * 64);
        #pragma unroll
        for (int s = 0; s < 16; ++s) *(bf16x4*)&xs[r][c + s * 64] = cvt4(tmp[s]);
    }

    const int lane = tid & 63;
    const int w    = tid >> 6;                    // 0..3 (colgroup, 48 cols)
    const int lr = lane & 15, lg = lane >> 4;

    f32x4 acc[3];
    #pragma unroll
    for (int nt = 0; nt < 3; ++nt) acc[nt] = (f32x4){0.f, 0.f, 0.f, 0.f};

    // per-lane base into WTB for this wave's rows
    const unsigned short* wrow = WTB + ((size_t)w * 48 + lr) * 64 + (lg << 3);

    __syncthreads();                              // xs ready (only barrier)

    #pragma unroll 4
    for (int kc = 0; kc < 16; ++kc) {
        #pragma unroll
        for (int st = 0; st < 2; ++st) {
            const bf16x8 af = *(const bf16x8*)&xs[lr][(kc << 6) + (st << 5) + (lg << 3)];
            #pragma unroll
            for (int nt = 0; nt < 3; ++nt) {
                const bf16x8 bf = *(const bf16x8*)(wrow + (size_t)kc * 12288
                                                   + nt * 1024 + (st << 5));
                acc[nt] = __builtin_amdgcn_mfma_f32_16x16x32_bf16(af, bf, acc[nt], 0, 0, 0);
            }
        }
    }

    const float qsc = 0.125f * 1.44269504088896340736f;  // scale * log2(e)
    #pragma unroll
    for (int nt = 0; nt < 3; ++nt) {
        const int gct = w * 3 + nt;                      // global 16-col tile
        if (gct < 8) {
            #pragma unroll
            for (int r = 0; r < 4; ++r) {
                const int row = m0 + (lg << 2) + r;
                const float vv = acc[nt][r];
                if (gct < 4) Qb[(size_t)row * DK + gct * 16 + lr] = f2bf(vv * qsc);
                else         Kb[(size_t)row * DK + (gct - 4) * 16 + lr] = f2bf(vv);
            }
        } else {
            // VT blocked: tile = (batch*32 + t/64), row d, col t%64; 8B store
            const int d = (gct - 8) * 16 + lr;
            const int t = m0 + (lg << 2);
            const int tb = t & (TSEQ - 1);
            const size_t tile = (size_t)(t >> 11) * 32 + (tb >> 6);
            ushort4 pk;
            pk.x = f2bf(acc[nt][0]); pk.y = f2bf(acc[nt][1]);
            pk.z = f2bf(acc[nt][2]); pk.w = f2bf(acc[nt][3]);
            *(ushort4*)&VT[(tile * DK + d) * 64 + (tb & 63)] = pk;
        }
    }
}

// ---------------- MFMA flash attention (R27: balance + blocked VT) ----------
__global__ __launch_bounds__(256, 2) void attn_kernel(
    const unsigned short* __restrict__ Qb, const unsigned short* __restrict__ Kb,
    const unsigned short* __restrict__ VT, float* __restrict__ O)
{
    __shared__ __align__(16) unsigned short P_lds[4][16][72];
    __shared__ float Opart[4][16][68];
    __shared__ float mpart[4][16];
    __shared__ float Lpart[4][16];

    const int lane = threadIdx.x & 63;
    const int w    = threadIdx.x >> 6;
    const int i    = blockIdx.x;
    const int half = i >> 8;                      // 0 = long, 1 = short
    const int k    = i & 255;
    const int batch = k & 3;
    const int j    = k >> 2;                      // 0..63
    const int qt_local = half ? j : (127 - j);
    const int q0 = (batch << 11) + (qt_local << 4);   // global row
    const int t0 = qt_local << 4;                 // within-batch row
    const int b  = batch;
    const int lr = lane & 15;
    const int lg = lane >> 4;

    const unsigned short* Qrow = Qb + (size_t)(q0 + lr) * DK + (lg << 3);
    const bf16x8 qf0 = *(const bf16x8*)(Qrow);
    const bf16x8 qf1 = *(const bf16x8*)(Qrow + 32);

    const unsigned short* Kbase = Kb + (size_t)b * TSEQ * DK;
    const unsigned short* Vbase = VT + (size_t)b * 32 * DK * 64;  // blocked tiles

    f32x4 oacc[4];
    #pragma unroll
    for (int dt = 0; dt < 4; ++dt) oacc[dt] = (f32x4){0.f, 0.f, 0.f, 0.f};
    float m[4] = {-INFINITY, -INFINITY, -INFINITY, -INFINITY};
    float L[4] = {0.f, 0.f, 0.f, 0.f};

    const int nkb = (t0 >> 6) + 1;                // 64-key blocks, within batch

    for (int kb = w; kb < nkb; kb += 4) {
        const int s0 = kb << 6;

        bf16x8 kf0[4], kf1[4];
        #pragma unroll
        for (int ct = 0; ct < 4; ++ct) {
            const unsigned short* Krow =
                Kbase + (size_t)(s0 + ct * 16 + lr) * DK + (lg << 3);
            kf0[ct] = *(const bf16x8*)(Krow);
            kf1[ct] = *(const bf16x8*)(Krow + 32);
        }

        bf16x8 vf0[4], vf1[4];
        {
            const unsigned short* Vtile = Vbase + (size_t)kb * DK * 64;
            #pragma unroll
            for (int dt = 0; dt < 4; ++dt) {
                const unsigned short* Vrow = Vtile + (dt * 16 + lr) * 64 + (lg << 3);
                vf0[dt] = *(const bf16x8*)(Vrow);
                vf1[dt] = *(const bf16x8*)(Vrow + 32);
            }
        }

        f32x4 s[4];
        #pragma unroll
        for (int ct = 0; ct < 4; ++ct) {
            f32x4 a = (f32x4){0.f, 0.f, 0.f, 0.f};
            a = __builtin_amdgcn_mfma_f32_16x16x32_bf16(qf0, kf0[ct], a, 0, 0, 0);
            a = __builtin_amdgcn_mfma_f32_16x16x32_bf16(qf1, kf1[ct], a, 0, 0, 0);
            s[ct] = a;
        }

        if (kb == nkb - 1) {
            #pragma unroll
            for (int ct = 0; ct < 4; ++ct)
                #pragma unroll
                for (int r = 0; r < 4; ++r)
                    if (s0 + ct * 16 + lr > t0 + lg * 4 + r) s[ct][r] = -INFINITY;
        }

        float pm[4];
        #pragma unroll
        for (int r = 0; r < 4; ++r)
            pm[r] = fmaxf(fmaxf(s[0][r], s[1][r]), fmaxf(s[2][r], s[3][r]));

        bool near = true;
        #pragma unroll
        for (int r = 0; r < 4; ++r)
            near = near && (pm[r] - m[r] <= 8.0f);

        if (!__all(near)) {
            float tmax[4];
            #pragma unroll
            for (int r = 0; r < 4; ++r) tmax[r] = pm[r];
            #pragma unroll
            for (int off = 1; off < 16; off <<= 1)
                #pragma unroll
                for (int r = 0; r < 4; ++r)
                    tmax[r] = fmaxf(tmax[r], __shfl_xor(tmax[r], off));

            float f[4];
            #pragma unroll
            for (int r = 0; r < 4; ++r) {
                const float mn = fmaxf(m[r], tmax[r]);
                f[r] = exp2f(m[r] - mn);
                m[r] = mn;
            }
            #pragma unroll
            for (int r = 0; r < 4; ++r) L[r] *= f[r];
            #pragma unroll
            for (int r = 0; r < 4; ++r) {
                oacc[0][r] *= f[r]; oacc[1][r] *= f[r];
                oacc[2][r] *= f[r]; oacc[3][r] *= f[r];
            }
        }

        float ps[4] = {0.f, 0.f, 0.f, 0.f};
        unsigned short pb[4][4];
        #pragma unroll
        for (int ct = 0; ct < 4; ++ct)
            #pragma unroll
            for (int r = 0; r < 4; ++r) {
                const float p = exp2f(s[ct][r] - m[r]);
                ps[r] += p;
                pb[ct][r] = f2bf(p);
            }
        #pragma unroll
        for (int r = 0; r < 4; ++r) L[r] += ps[r];

        #pragma unroll
        for (int ct = 0; ct < 4; ++ct)
            #pragma unroll
            for (int r = 0; r < 4; ++r)
                P_lds[w][lg * 4 + r][ct * 16 + lr] = pb[ct][r];
        asm volatile("s_waitcnt lgkmcnt(0)" ::: "memory");
        const bf16x8 pf0 = *(const bf16x8*)&P_lds[w][lr][(lg << 3)];
        const bf16x8 pf1 = *(const bf16x8*)&P_lds[w][lr][32 + (lg << 3)];

        #pragma unroll
        for (int dt = 0; dt < 4; ++dt) {
            oacc[dt] = __builtin_amdgcn_mfma_f32_16x16x32_bf16(pf0, vf0[dt], oacc[dt], 0, 0, 0);
            oacc[dt] = __builtin_amdgcn_mfma_f32_16x16x32_bf16(pf1, vf1[dt], oacc[dt], 0, 0, 0);
        }
    }

    #pragma unroll
    for (int off = 1; off < 16; off <<= 1)
        #pragma unroll
        for (int r = 0; r < 4; ++r) L[r] += __shfl_xor(L[r], off);

    #pragma unroll
    for (int dt = 0; dt < 4; ++dt)
        #pragma unroll
        for (int r = 0; r < 4; ++r)
            Opart[w][(lg << 2) + r][dt * 16 + lr] = oacc[dt][r];
    if (lr == 0) {
        #pragma unroll
        for (int r = 0; r < 4; ++r) {
            mpart[w][(lg << 2) + r] = m[r];
            Lpart[w][(lg << 2) + r] = L[r];
        }
    }
    __syncthreads();

    #pragma unroll
    for (int r = 0; r < 4; ++r) {
        const int row = (lg << 2) + r;
        const float M = fmaxf(fmaxf(mpart[0][row], mpart[1][row]),
                              fmaxf(mpart[2][row], mpart[3][row]));
        float Lf = 0.f, o = 0.f;
        #pragma unroll
        for (int v = 0; v < 4; ++v) {
            const float fv = exp2f(mpart[v][row] - M);
            Lf += fv * Lpart[v][row];
            o  += fv * Opart[v][row][(w << 4) + lr];
        }
        O[(size_t)(q0 + row) * DK + (w << 4) + lr] = o / Lf;
    }
}

extern "C" void kernel_launch(void* const* d_in, const int* in_sizes, int n_in,
                              void* d_out, int out_size, void* d_ws, size_t ws_size,
                              hipStream_t stream) {
    const float* x  = (const float*)d_in[0];
    const float* Wq = (const float*)d_in[1];
    const float* Wk = (const float*)d_in[2];
    const float* Wv = (const float*)d_in[3];
    float* O = (float*)d_out;

    unsigned short* Qb  = (unsigned short*)d_ws;                // 1 MB
    unsigned short* Kb  = Qb + (size_t)BT * DK;                 // 1 MB
    unsigned short* VT  = Kb + (size_t)BT * DK;                 // 1 MB (blocked)
    unsigned short* WTB = VT + (size_t)BT * DK;                 // 384 KB (chunked)

    wt_kernel  <<<dim3(48),  dim3(256), 0, stream>>>(Wq, Wk, Wv, WTB);
    proj_kernel<<<dim3(512), dim3(256), 0, stream>>>(x, WTB, Qb, Kb, VT);
    attn_kernel<<<dim3(512), dim3(256), 0, stream>>>(Qb, Kb, VT, O);
}

// Round 29
// 41.966 us; speedup vs baseline: 1.3180x; 1.3180x over previous
//
#include <hip/hip_runtime.h>
#include <math.h>

#define BT    8192
#define TSEQ  2048
#define DIN   1024
#define DK    64

typedef __attribute__((ext_vector_type(8))) short bf16x8;
typedef __attribute__((ext_vector_type(4))) short bf16x4;
typedef __attribute__((ext_vector_type(4))) float f32x4;

static __device__ inline unsigned short f2bf(float f) {
    union { float f; unsigned u; } v; v.f = f;
    unsigned r = v.u + 0x7fff + ((v.u >> 16) & 1);   // RNE
    return (unsigned short)(r >> 16);
}

static __device__ inline bf16x4 cvt4(float4 a) {
    bf16x4 r;
    r[0] = (short)f2bf(a.x); r[1] = (short)f2bf(a.y);
    r[2] = (short)f2bf(a.z); r[3] = (short)f2bf(a.w);
    return r;
}

// ---------------- WT[mat*64+n][k] = bf16(W[k][n]) : [192][1024] -------------
__global__ __launch_bounds__(256) void wt_kernel(
    const float* __restrict__ Wq, const float* __restrict__ Wk,
    const float* __restrict__ Wv, unsigned short* __restrict__ WT)
{
    __shared__ float ws[64][65];
    const int tid = threadIdx.x;
    const int mat = blockIdx.x >> 4;               // 0..2
    const int k0  = (blockIdx.x & 15) << 6;        // 0..960
    const float* W = (mat == 0) ? Wq : ((mat == 1) ? Wk : Wv);

    const int j = tid & 63;
    for (int i = tid >> 6; i < 64; i += 4)
        ws[i][j] = W[(size_t)(k0 + i) * DK + j];
    __syncthreads();

    const int n  = tid & 63;
    const int c0 = (tid >> 6) << 4;
    unsigned short* dst = WT + (size_t)(mat * 64 + n) * DIN + k0 + c0;
    #pragma unroll
    for (int c = 0; c < 16; ++c) dst[c] = f2bf(ws[c0 + c][n]);
}

// ---------------- MFMA projection: barrier-free per-wave WT pipeline (R18) --
__global__ __launch_bounds__(256, 2) void proj_kernel(
    const float* __restrict__ x, const unsigned short* __restrict__ WT,
    unsigned short* __restrict__ Qb, unsigned short* __restrict__ Kb,
    unsigned short* __restrict__ VT)
{
    __shared__ unsigned short xs[16][1032];        // 33.0 KB
    __shared__ unsigned short wtb[192][72];        // 27.6 KB, 48 rows/wave
    const int tid = threadIdx.x;
    const int m0 = blockIdx.x * 16;

    {
        const int r = tid >> 4;
        const int c = (tid & 15) << 2;
        const float* src = x + (size_t)(m0 + r) * DIN + c;
        float4 tmp[16];
        #pragma unroll
        for (int s = 0; s < 16; ++s) tmp[s] = *(const float4*)(src + s * 64);
        #pragma unroll
        for (int s = 0; s < 16; ++s) *(bf16x4*)&xs[r][c + s * 64] = cvt4(tmp[s]);
    }

    const int lane = tid & 63;
    const int w    = tid >> 6;                    // 0..3 (colgroup, 48 cols)
    const int lr = lane & 15, lg = lane >> 4;

    f32x4 acc[3];
    #pragma unroll
    for (int nt = 0; nt < 3; ++nt) acc[nt] = (f32x4){0.f, 0.f, 0.f, 0.f};

    const unsigned short* wt_w = WT + (size_t)w * 48 * DIN;   // wave's rows
    bf16x8 cur[6], nxt[6];
    #pragma unroll
    for (int i = 0; i < 6; ++i) {                 // prologue: chunk 0 loads
        const int c = lane + i * 64;              // 0..383
        const int nl = c >> 3;                    // local row 0..47
        const int sl = c & 7;                     // 16B slot
        cur[i] = *(const bf16x8*)(wt_w + (size_t)nl * DIN + (sl << 3));
    }

    __syncthreads();                              // xs ready (only barrier)

    for (int kc = 0; kc < 16; ++kc) {
        const int k0 = kc << 6;

        if (kc + 1 < 16) {
            #pragma unroll
            for (int i = 0; i < 6; ++i) {
                const int c = lane + i * 64;
                const int nl = c >> 3;
                const int sl = c & 7;
                nxt[i] = *(const bf16x8*)(wt_w + (size_t)nl * DIN
                                          + (k0 + 64) + (sl << 3));
            }
        }

        #pragma unroll
        for (int i = 0; i < 6; ++i) {
            const int c = lane + i * 64;
            const int n = w * 48 + (c >> 3);
            const int sl = c & 7;
            *(bf16x8*)&wtb[n][((sl + n) & 7) << 3] = cur[i];
        }
        asm volatile("s_waitcnt lgkmcnt(0)" ::: "memory");  // wave-local W->R

        #pragma unroll
        for (int st = 0; st < 2; ++st) {
            const bf16x8 af = *(const bf16x8*)&xs[lr][k0 + (st << 5) + (lg << 3)];
            #pragma unroll
            for (int nt = 0; nt < 3; ++nt) {
                const int n = w * 48 + nt * 16 + lr;
                const int sl = (st << 2) + lg;
                const bf16x8 bf = *(const bf16x8*)&wtb[n][((sl + n) & 7) << 3];
                acc[nt] = __builtin_amdgcn_mfma_f32_16x16x32_bf16(af, bf, acc[nt], 0, 0, 0);
            }
        }

        if (kc + 1 < 16) {
            #pragma unroll
            for (int i = 0; i < 6; ++i) cur[i] = nxt[i];
        }
    }

    const float qsc = 0.125f * 1.44269504088896340736f;  // scale * log2(e)
    #pragma unroll
    for (int nt = 0; nt < 3; ++nt) {
        const int gct = w * 3 + nt;                      // global 16-col tile
        if (gct < 8) {
            #pragma unroll
            for (int r = 0; r < 4; ++r) {
                const int row = m0 + (lg << 2) + r;
                const float vv = acc[nt][r];
                if (gct < 4) Qb[(size_t)row * DK + gct * 16 + lr] = f2bf(vv * qsc);
                else         Kb[(size_t)row * DK + (gct - 4) * 16 + lr] = f2bf(vv);
            }
        } else {
            // VT blocked: tile = (batch*32 + t/64), row d, col t%64; 8B store
            const int d = (gct - 8) * 16 + lr;
            const int t = m0 + (lg << 2);
            const int tb = t & (TSEQ - 1);
            const size_t tile = (size_t)(t >> 11) * 32 + (tb >> 6);
            ushort4 pk;
            pk.x = f2bf(acc[nt][0]); pk.y = f2bf(acc[nt][1]);
            pk.z = f2bf(acc[nt][2]); pk.w = f2bf(acc[nt][3]);
            *(ushort4*)&VT[(tile * DK + d) * 64 + (tb & 63)] = pk;
        }
    }
}

// ---------------- MFMA flash attention (R19 balance + blocked VT, no rotate) -
__global__ __launch_bounds__(256, 2) void attn_kernel(
    const unsigned short* __restrict__ Qb, const unsigned short* __restrict__ Kb,
    const unsigned short* __restrict__ VT, float* __restrict__ O)
{
    __shared__ __align__(16) unsigned short P_lds[4][16][72];
    __shared__ float Opart[4][16][68];
    __shared__ float mpart[4][16];
    __shared__ float Lpart[4][16];

    const int lane = threadIdx.x & 63;
    const int w    = threadIdx.x >> 6;
    const int i    = blockIdx.x;
    const int half = i >> 8;                      // 0 = long, 1 = short
    const int k    = i & 255;
    const int batch = k & 3;
    const int j    = k >> 2;                      // 0..63
    const int qt_local = half ? j : (127 - j);
    const int q0 = (batch << 11) + (qt_local << 4);   // global row
    const int t0 = qt_local << 4;                 // within-batch row
    const int b  = batch;
    const int lr = lane & 15;
    const int lg = lane >> 4;

    const unsigned short* Qrow = Qb + (size_t)(q0 + lr) * DK + (lg << 3);
    const bf16x8 qf0 = *(const bf16x8*)(Qrow);
    const bf16x8 qf1 = *(const bf16x8*)(Qrow + 32);

    const unsigned short* Kbase = Kb + (size_t)b * TSEQ * DK;
    const unsigned short* Vbase = VT + (size_t)b * 32 * DK * 64;  // blocked tiles

    f32x4 oacc[4];
    #pragma unroll
    for (int dt = 0; dt < 4; ++dt) oacc[dt] = (f32x4){0.f, 0.f, 0.f, 0.f};
    float m[4] = {-INFINITY, -INFINITY, -INFINITY, -INFINITY};
    float L[4] = {0.f, 0.f, 0.f, 0.f};

    const int nkb = (t0 >> 6) + 1;                // 64-key blocks, within batch

    for (int kb = w; kb < nkb; kb += 4) {
        const int s0 = kb << 6;

        bf16x8 kf0[4], kf1[4];
        #pragma unroll
        for (int ct = 0; ct < 4; ++ct) {
            const unsigned short* Krow =
                Kbase + (size_t)(s0 + ct * 16 + lr) * DK + (lg << 3);
            kf0[ct] = *(const bf16x8*)(Krow);
            kf1[ct] = *(const bf16x8*)(Krow + 32);
        }

        bf16x8 vf0[4], vf1[4];
        {
            const unsigned short* Vtile = Vbase + (size_t)kb * DK * 64;
            #pragma unroll
            for (int dt = 0; dt < 4; ++dt) {
                const unsigned short* Vrow = Vtile + (dt * 16 + lr) * 64 + (lg << 3);
                vf0[dt] = *(const bf16x8*)(Vrow);
                vf1[dt] = *(const bf16x8*)(Vrow + 32);
            }
        }

        f32x4 s[4];
        #pragma unroll
        for (int ct = 0; ct < 4; ++ct) {
            f32x4 a = (f32x4){0.f, 0.f, 0.f, 0.f};
            a = __builtin_amdgcn_mfma_f32_16x16x32_bf16(qf0, kf0[ct], a, 0, 0, 0);
            a = __builtin_amdgcn_mfma_f32_16x16x32_bf16(qf1, kf1[ct], a, 0, 0, 0);
            s[ct] = a;
        }

        if (kb == nkb - 1) {
            #pragma unroll
            for (int ct = 0; ct < 4; ++ct)
                #pragma unroll
                for (int r = 0; r < 4; ++r)
                    if (s0 + ct * 16 + lr > t0 + lg * 4 + r) s[ct][r] = -INFINITY;
        }

        float pm[4];
        #pragma unroll
        for (int r = 0; r < 4; ++r)
            pm[r] = fmaxf(fmaxf(s[0][r], s[1][r]), fmaxf(s[2][r], s[3][r]));

        bool near = true;
        #pragma unroll
        for (int r = 0; r < 4; ++r)
            near = near && (pm[r] - m[r] <= 8.0f);

        if (!__all(near)) {
            float tmax[4];
            #pragma unroll
            for (int r = 0; r < 4; ++r) tmax[r] = pm[r];
            #pragma unroll
            for (int off = 1; off < 16; off <<= 1)
                #pragma unroll
                for (int r = 0; r < 4; ++r)
                    tmax[r] = fmaxf(tmax[r], __shfl_xor(tmax[r], off));

            float f[4];
            #pragma unroll
            for (int r = 0; r < 4; ++r) {
                const float mn = fmaxf(m[r], tmax[r]);
                f[r] = exp2f(m[r] - mn);
                m[r] = mn;
            }
            #pragma unroll
            for (int r = 0; r < 4; ++r) L[r] *= f[r];
            #pragma unroll
            for (int r = 0; r < 4; ++r) {
                oacc[0][r] *= f[r]; oacc[1][r] *= f[r];
                oacc[2][r] *= f[r]; oacc[3][r] *= f[r];
            }
        }

        float ps[4] = {0.f, 0.f, 0.f, 0.f};
        unsigned short pb[4][4];
        #pragma unroll
        for (int ct = 0; ct < 4; ++ct)
            #pragma unroll
            for (int r = 0; r < 4; ++r) {
                const float p = exp2f(s[ct][r] - m[r]);
                ps[r] += p;
                pb[ct][r] = f2bf(p);
            }
        #pragma unroll
        for (int r = 0; r < 4; ++r) L[r] += ps[r];

        #pragma unroll
        for (int ct = 0; ct < 4; ++ct)
            #pragma unroll
            for (int r = 0; r < 4; ++r)
                P_lds[w][lg * 4 + r][ct * 16 + lr] = pb[ct][r];
        asm volatile("s_waitcnt lgkmcnt(0)" ::: "memory");
        const bf16x8 pf0 = *(const bf16x8*)&P_lds[w][lr][(lg << 3)];
        const bf16x8 pf1 = *(const bf16x8*)&P_lds[w][lr][32 + (lg << 3)];

        #pragma unroll
        for (int dt = 0; dt < 4; ++dt) {
            oacc[dt] = __builtin_amdgcn_mfma_f32_16x16x32_bf16(pf0, vf0[dt], oacc[dt], 0, 0, 0);
            oacc[dt] = __builtin_amdgcn_mfma_f32_16x16x32_bf16(pf1, vf1[dt], oacc[dt], 0, 0, 0);
        }
    }

    #pragma unroll
    for (int off = 1; off < 16; off <<= 1)
        #pragma unroll
        for (int r = 0; r < 4; ++r) L[r] += __shfl_xor(L[r], off);

    #pragma unroll
    for (int dt = 0; dt < 4; ++dt)
        #pragma unroll
        for (int r = 0; r < 4; ++r)
            Opart[w][(lg << 2) + r][dt * 16 + lr] = oacc[dt][r];
    if (lr == 0) {
        #pragma unroll
        for (int r = 0; r < 4; ++r) {
            mpart[w][(lg << 2) + r] = m[r];
            Lpart[w][(lg << 2) + r] = L[r];
        }
    }
    __syncthreads();

    #pragma unroll
    for (int r = 0; r < 4; ++r) {
        const int row = (lg << 2) + r;
        const float M = fmaxf(fmaxf(mpart[0][row], mpart[1][row]),
                              fmaxf(mpart[2][row], mpart[3][row]));
        float Lf = 0.f, o = 0.f;
        #pragma unroll
        for (int v = 0; v < 4; ++v) {
            const float fv = exp2f(mpart[v][row] - M);
            Lf += fv * Lpart[v][row];
            o  += fv * Opart[v][row][(w << 4) + lr];
        }
        O[(size_t)(q0 + row) * DK + (w << 4) + lr] = o / Lf;
    }
}

extern "C" void kernel_launch(void* const* d_in, const int* in_sizes, int n_in,
                              void* d_out, int out_size, void* d_ws, size_t ws_size,
                              hipStream_t stream) {
    const float* x  = (const float*)d_in[0];
    const float* Wq = (const float*)d_in[1];
    const float* Wk = (const float*)d_in[2];
    const float* Wv = (const float*)d_in[3];
    float* O = (float*)d_out;

    unsigned short* Qb = (unsigned short*)d_ws;                 // 1 MB
    unsigned short* Kb = Qb + (size_t)BT * DK;                  // 1 MB
    unsigned short* VT = Kb + (size_t)BT * DK;                  // 1 MB (blocked)
    unsigned short* WT = VT + (size_t)BT * DK;                  // 384 KB

    wt_kernel  <<<dim3(48),  dim3(256), 0, stream>>>(Wq, Wk, Wv, WT);
    proj_kernel<<<dim3(512), dim3(256), 0, stream>>>(x, WT, Qb, Kb, VT);
    attn_kernel<<<dim3(512), dim3(256), 0, stream>>>(Qb, Kb, VT, O);
}